// Round 14
// baseline (18.397 us; speedup 1.0000x reference)
//
#include <hip/hip_runtime.h>
#include <hip/hip_bf16.h>
#include <hip/hip_fp16.h>

// HeteroSoap via MFMA: c[s*4+n][ab] = sum_atoms f_sn * Y_ab = 16x16 GEMM, K=N.
// Round 14 = round 13 VERBATIM with ONE variable changed: NB 512 -> 1024
// (2 -> 4 blocks/CU, 2 -> 4 waves/SIMD). r13 analysis: kernel is ~20x above
// its instruction-issue floor -> latency-bound; more co-resident waves is
// the direct attack. NB was never isolated cleanly before (r5/r9/r11 all
// confounded NB with datapath changes).
// Datapath (proven r13): packed-f16 harmonics (2 atoms/lane, atom0 lo/atom1
// hi), radial in f32, staged dword = f16 pair, fragment = one ds_read_b128,
// zero unpack, v_mfma_f32_16x16x32_f16. Same (pair,elem)->atom map for A and
// B so MFMA internal k-order cancels. XOR swizzle idx^((c&7)<<2) identical
// on write and read. C/D layout per m89. Tail: reduce+finalize ticket (r10).

typedef float f32x4 __attribute__((ext_vector_type(4)));
typedef unsigned int uint4v __attribute__((ext_vector_type(4)));
typedef _Float16 h2 __attribute__((ext_vector_type(2)));
typedef _Float16 half8 __attribute__((ext_vector_type(8)));

#define NB 1024

__global__ void __launch_bounds__(256) soap_accum(
    const float* __restrict__ coo, const int* __restrict__ numbers,
    int N, float* __restrict__ partials, float* __restrict__ c_ws,
    int* __restrict__ counter)
{
    __shared__ unsigned int lT[4][2][16][64];  // [wave][A|B][comp][pair] 32 KB

    // Per-launch init of fused-tail state (accum ends before reduce starts).
    if (blockIdx.x == 0) {
        if (threadIdx.x < 256) c_ws[threadIdx.x] = 0.f;
        if (threadIdx.x == 0) *counter = 0;
    }

    const int lane = threadIdx.x & 63;
    const int w = threadIdx.x >> 6;
    const int g = lane >> 4;            // k-group
    const int comp = lane & 15;         // fragment index dim (A row / B col)

    unsigned int* lA = &lT[w][0][0][0];
    unsigned int* lB = &lT[w][1][0][0];

    // Loop-invariant read offsets: MFMA m covers pairs 16m..16m+15; lane
    // (comp,g) reads 4 consecutive swizzled dwords = pairs 16m+4g..+3 =
    // atoms {16m+4g+j, 16m+4g+j+64}. Same map for A and B.
    const unsigned swz = (unsigned)((comp & 7) << 2);
    const unsigned rbase = (unsigned)(comp << 6);
    unsigned rd[4];
#pragma unroll
    for (int m = 0; m < 4; ++m)
        rd[m] = rbase + ((unsigned)(16 * m + 4 * g) ^ swz);

    f32x4 acc = {0.f, 0.f, 0.f, 0.f};

    const int stride = NB * 512;        // 4 waves x 128 atoms per block per iter
    for (int base = (blockIdx.x * 4 + w) * 128; base < N; base += stride) {
        int i0 = base + lane, i1 = base + 64 + lane;
        int ic0 = i0 < N ? i0 : N - 1, ic1 = i1 < N ? i1 : N - 1;
        float X0 = coo[3 * ic0], Y0_ = coo[3 * ic0 + 1], Z0 = coo[3 * ic0 + 2];
        float X1 = coo[3 * ic1], Y1_ = coo[3 * ic1 + 1], Z1 = coo[3 * ic1 + 2];
        int num0 = i0 < N ? numbers[ic0] : -1;
        int num1 = i1 < N ? numbers[ic1] : -1;

        // Radial in f32 per atom (exp-arg precision), store f16.
        float x0 = X0 * 0.5f, y0 = Y0_ * 0.5f, z0 = Z0 * 0.5f;
        float x1 = X1 * 0.5f, y1 = Y1_ * 0.5f, z1 = Z1 * 0.5f;
        float r20 = x0 * x0 + y0 * y0 + z0 * z0;
        float r21 = x1 * x1 + y1 * y1 + z1 * z1;
        float t0 = fmaxf(1.f - sqrtf(r20) * (1.f / 3.f), 0.f);
        float t1 = fmaxf(1.f - sqrtf(r21) * (1.f / 3.f), 0.f);
        float f00 = __expf(-0.5f * r20) * t0 * t0;
        float f01 = __expf(-0.5f * r21) * t1 * t1;

        h2 fpk[4];
        fpk[0] = (h2){(_Float16)f00, (_Float16)f01};
        fpk[1] = (h2){(_Float16)(f00 * r20), (_Float16)(f01 * r21)};
        fpk[2] = (h2){(_Float16)(f00 * r20 * r20), (_Float16)(f01 * r21 * r21)};
        fpk[3] = (h2){(_Float16)(f00 * r20 * r20 * r20), (_Float16)(f01 * r21 * r21 * r21)};

        // Species one-hot as f16 pair masks (invalid atom -> num=-1 -> 0).
        h2 msk[4];
#pragma unroll
        for (int s = 0; s < 4; ++s)
            msk[s] = (h2){(_Float16)(num0 == s ? 1.f : 0.f),
                          (_Float16)(num1 == s ? 1.f : 0.f)};

        // Packed f16 inputs for the harmonic chain (atom0 lo, atom1 hi).
        h2 xp = (h2){(_Float16)x0, (_Float16)x1};
        h2 yp = (h2){(_Float16)y0, (_Float16)y1};
        h2 zp = (h2){(_Float16)z0, (_Float16)z1};
        h2 rp = (h2){(_Float16)r20, (_Float16)r21};

        // Solid harmonics, packed pairs (v_pk_mul/fma_f16):
        h2 re11 = (_Float16)-0.34549414947133550f * xp;
        h2 im11 = (_Float16)-0.34549414947133550f * yp;
        h2 re10 = (_Float16) 0.48860251190291992f * zp;
        h2 re22 = (_Float16)-1.11803398874989490f * (xp * re11 - yp * im11);
        h2 im22 = (_Float16)-1.11803398874989490f * (xp * im11 + yp * re11);
        h2 re21 = (_Float16) 2.23606797749978970f * (zp * re11);
        h2 im21 = (_Float16) 2.23606797749978970f * (zp * im11);
        h2 re20 = (_Float16) 1.93649167310370850f * (zp * re10 - (_Float16)0.16286750396763996f * rp);
        h2 re33 = (_Float16)-1.08012344973464350f * (xp * re22 - yp * im22);
        h2 im33 = (_Float16)-1.08012344973464350f * (xp * im22 + yp * re22);
        h2 re32 = (_Float16) 2.64575131106459070f * (zp * re22);
        h2 im32 = (_Float16) 2.64575131106459070f * (zp * im22);
        h2 re31 = (_Float16) 2.09165006633518890f * (zp * re21 - (_Float16)0.44721359549995793f * (rp * re11));
        h2 im31 = (_Float16) 2.09165006633518890f * (zp * im21 - (_Float16)0.44721359549995793f * (rp * im11));
        h2 re30 = (_Float16) 1.97202659436653870f * (zp * re20 - (_Float16)0.51639777949432220f * (rp * re10));

        h2 ypk[16];
        ypk[0] = (h2){(_Float16)0.28209479177387814f, (_Float16)0.28209479177387814f};
        ypk[1] = im11; ypk[2]  = im22; ypk[3]  = im33;
        ypk[4] = re11; ypk[5]  = re10; ypk[6]  = im21; ypk[7]  = im32;
        ypk[8] = re22; ypk[9]  = re21; ypk[10] = re20; ypk[11] = im31;
        ypk[12] = re33; ypk[13] = re32; ypk[14] = re31; ypk[15] = re30;

        // Swizzled stores: lane owns pair-column `lane`; one b32 per tile/comp.
#pragma unroll
        for (int c = 0; c < 16; ++c) {
            h2 fs = fpk[c & 3] * msk[c >> 2];
            union { h2 h; unsigned u; } ua, ub;
            ua.h = fs; ub.h = ypk[c];
            unsigned idx = (unsigned)(c << 6) + ((unsigned)lane ^ ((unsigned)(c & 7) << 2));
            lA[idx] = ua.u;
            lB[idx] = ub.u;
        }

        // 4 MFMAs (32 atoms each); wave-private tile, in-order LDS per wave.
#pragma unroll
        for (int m = 0; m < 4; ++m) {
            union { uint4v q; half8 h; } A, B;
            A.q = *(const uint4v*)&lA[rd[m]];
            B.q = *(const uint4v*)&lB[rd[m]];
            acc = __builtin_amdgcn_mfma_f32_16x16x32_f16(A.h, B.h, acc, 0, 0, 0);
        }
    }

    // C/D layout (m89): lane, reg rr -> c[i=(lane>>4)*4+rr][j=lane&15].
    // Reuse this wave's (idle, wave-private) tile as the reduce buffer.
    float* credw = (float*)&lT[w][0][0][0];
#pragma unroll
    for (int rr = 0; rr < 4; ++rr)
        credw[((lane >> 4) * 4 + rr) * 16 + (lane & 15)] = acc[rr];
    __syncthreads();

    int tt = threadIdx.x;
    partials[blockIdx.x * 256 + tt] =
        ((float*)&lT[0][0][0][0])[tt] + ((float*)&lT[1][0][0][0])[tt] +
        ((float*)&lT[2][0][0][0])[tt] + ((float*)&lT[3][0][0][0])[tt];
}

// Fused reduce + finalize, 32 blocks. Each block sums its slice of partials
// into c_ws atomically; last block to finish does the Yr/Yi/nnl contraction.
__global__ void __launch_bounds__(256) soap_reduce_final(
    const float* __restrict__ partials, float* __restrict__ c_ws,
    int* __restrict__ counter, float* __restrict__ out)
{
    __shared__ float cs[256];
    __shared__ int lastflag;
    int t = threadIdx.x;

    float v = 0.f;
    for (int r = blockIdx.x; r < NB; r += 32)
        v += partials[r * 256 + t];           // coalesced, 32 iters
    atomicAdd(&c_ws[t], v);                   // 32 adds/address, device scope
    __syncthreads();
    if (t == 0) {
        __threadfence();                      // release our adds
        lastflag = (atomicAdd(counter, 1) == 31);
    }
    __syncthreads();
    if (!lastflag) return;

    __threadfence();                          // acquire other blocks' adds
    cs[t] = __hip_atomic_load(&c_ws[t], __ATOMIC_RELAXED,
                              __HIP_MEMORY_SCOPE_AGENT);  // L1-bypassing load
    __syncthreads();

    // p1[a,b,n,m,l] = sum_{j<=l} w_j c[b,m,l,j] c[a,n,l,j] (w=1 if j==l else 2)
    // p2[a,b,n,m,l] = sum_{i<l}  2  c[b,m,i,l] c[a,n,i,l]
    // out = (p1+p2) * nnl[n,m,l]
    const float fact[7] = {1.f, 1.f, 2.f, 6.f, 24.f, 120.f, 720.f};
#pragma unroll
    for (int k = 0; k < 4; ++k) {
        int o = k * 256 + t;
        int l = o & 3, m = (o >> 2) & 3, n = (o >> 4) & 3,
            b = (o >> 6) & 3, a = (o >> 8) & 3;
        const float* cbm = &cs[(b * 4 + m) * 16];
        const float* can = &cs[(a * 4 + n) * 16];
        float vv = 0.f;
        for (int j = 0; j <= l; ++j) {
            float wgt = (j == l) ? 1.f : 2.f;
            vv += wgt * cbm[l * 4 + j] * can[l * 4 + j];
        }
        for (int i = 0; i < l; ++i)
            vv += 2.f * cbm[i * 4 + l] * can[i * 4 + l];
        float an = 1.0f / ((float)(2 * l + 1) * (float)(1 << (2 * n + l)) * fact[n] * fact[n + l]);
        float am = 1.0f / ((float)(2 * l + 1) * (float)(1 << (2 * m + l)) * fact[m] * fact[m + l]);
        out[o] = vv * sqrtf(an * am);
    }
}

extern "C" void kernel_launch(void* const* d_in, const int* in_sizes, int n_in,
                              void* d_out, int out_size, void* d_ws, size_t ws_size,
                              hipStream_t stream)
{
    const float* coo = (const float*)d_in[0];
    const int* numbers = (const int*)d_in[1];
    int N = in_sizes[1];                 // 1,000,000 atoms

    float* c_ws = (float*)d_ws;          // [256] accumulated c
    int* counter = (int*)((float*)d_ws + 256);  // ticket counter
    float* partials = (float*)d_ws + 512;       // [NB*256] stage-1 partials
    // ws requirement: (512 + 262144) * 4 B ~= 1.05 MB.

    hipLaunchKernelGGL(soap_accum, dim3(NB), dim3(256), 0, stream,
                       coo, numbers, N, partials, c_ws, counter);
    hipLaunchKernelGGL(soap_reduce_final, dim3(32), dim3(256), 0, stream,
                       partials, c_ws, counter, (float*)d_out);
}